// Round 3
// baseline (699.255 us; speedup 1.0000x reference)
//
#include <hip/hip_runtime.h>
#include <cstddef>

#define LOG2PI_F 1.8378770664093453f
#define LOG2E_F  1.4426950408889634f

__device__ __forceinline__ float wave_sum(float v) {
#pragma unroll
    for (int o = 32; o >= 1; o >>= 1) v += __shfl_xor(v, o, 64);
    return v;
}
__device__ __forceinline__ float wave_max(float v) {
#pragma unroll
    for (int o = 32; o >= 1; o >>= 1) v = fmaxf(v, __shfl_xor(v, o, 64));
    return v;
}
__device__ __forceinline__ float wave_scan_incl(float v, int lane) {
#pragma unroll
    for (int o = 1; o < 64; o <<= 1) {
        float t = __shfl_up(v, o, 64);
        if (lane >= o) v += t;
    }
    return v;
}

// ---------------------------------------------------------------------------
// init: logrb, zero counts + pC
__global__ void k_init(const float* __restrict__ rho_bias, float* __restrict__ logrb,
                       int* __restrict__ counts, float* __restrict__ pC, int G_total) {
    int i = blockIdx.x * blockDim.x + threadIdx.x;
    if (i < G_total) logrb[i] = __logf(rho_bias[i]);
    if (i < 512) counts[i] = 0;
    if (i == 512 + 0) pC[0] = 0.f;
}

// ---------------------------------------------------------------------------
// Fused per-gene prep: lwT transpose (scaled by log2e) + prior ssq + packed
// spline tables. pk[g][j]: (uh[j+1]*log2e, 0.5*w[j], loc[j+1], 0) per level;
// pk[g][127] = level-start uh*log2e.
__global__ void k_prep(const int* __restrict__ genes_oi,
                       const float* __restrict__ uh, const float* __restrict__ uw,
                       const float* __restrict__ lw, const float* __restrict__ rw,
                       float4* __restrict__ pk, float* __restrict__ lwT,
                       float* __restrict__ pB) {
    const int g = blockIdx.x;
    const int tid = threadIdx.x;
    const int gs = genes_oi[g];

    float acc = 0.f;
    if (tid < 224) {
        const float* src = lw + (size_t)gs * 3584;
        float* dst = lwT + (size_t)g * 3584;
        float vv[16];
#pragma unroll
        for (int l = 0; l < 16; ++l) {
            float v = src[l * 224 + tid];
            vv[l] = v * LOG2E_F;
            acc = fmaf(v, v, acc);
        }
        float4* d4 = (float4*)(dst + (size_t)tid * 16);
#pragma unroll
        for (int q = 0; q < 4; ++q)
            d4[q] = make_float4(vv[4 * q + 0], vv[4 * q + 1], vv[4 * q + 2], vv[4 * q + 3]);
    }
    if (tid < 16) { float v = rw[(size_t)gs * 16 + tid]; acc = fmaf(v, v, acc); }

    if (tid < 64) {
        const int t = tid;
        const float* uhg = uh + (size_t)gs * 224;
        const float* uwg = uw + (size_t)gs * 221;
        float4* pkg = pk + (size_t)g * 224;
        const int NH[3] = {128, 64, 32};
        const int OH[3] = {0, 128, 192};
        const int OW[3] = {0, 127, 190};
        const int SO[3] = {0, 128, 191};
#pragma unroll
        for (int lev = 0; lev < 3; ++lev) {
            const int nw = NH[lev] - 1;
            float v0 = (t < nw)      ? uwg[OW[lev] + t]      : -INFINITY;
            float v1 = (t + 64 < nw) ? uwg[OW[lev] + t + 64] : -INFINITY;
            float mx = wave_max(fmaxf(v0, v1));
            float e0 = (t < nw)      ? __expf(v0 - mx) : 0.f;
            float e1 = (t + 64 < nw) ? __expf(v1 - mx) : 0.f;
            float inv = 1.0f / wave_sum(e0 + e1);
            float w0 = e0 * inv, w1 = e1 * inv;
            float i0 = wave_scan_incl(w0, t);
            float tot0 = __shfl(i0, 63, 64);
            float i1 = wave_scan_incl(w1, t) + tot0;
            if (t < nw) {
                float loc = (t == nw - 1) ? 1.0f : i0;
                pkg[SO[lev] + t] = make_float4(uhg[OH[lev] + t + 1] * LOG2E_F, 0.5f * w0, loc, 0.f);
            }
            if (t + 64 < nw) {
                int j = t + 64;
                float loc = (j == nw - 1) ? 1.0f : i1;
                pkg[SO[lev] + j] = make_float4(uhg[OH[lev] + j + 1] * LOG2E_F, 0.5f * w1, loc, 0.f);
            }
        }
        if (t == 0)
            pkg[127] = make_float4(uhg[0] * LOG2E_F, uhg[128] * LOG2E_F, uhg[192] * LOG2E_F, 0.f);
    }

    __shared__ float sm[256];
    sm[tid] = acc;
    __syncthreads();
    for (int o = 128; o > 0; o >>= 1) { if (tid < o) sm[tid] += sm[tid + o]; __syncthreads(); }
    if (tid == 0) pB[g] = 0.5f * sm[0] + 0.5f * LOG2PI_F * (3584.0f + 16.0f);
}

// ---------------------------------------------------------------------------
// Per-cell log-sum-exp over all G_total genes of (log rho_bias + cl·rw).
__global__ void k_lse(const float* __restrict__ clustering, const float* __restrict__ rw,
                      const float* __restrict__ logrb, float* __restrict__ lse, int G_total) {
    const int b = blockIdx.x;
    const int tid = threadIdx.x;
    __shared__ float cl_s[16];
    if (tid < 16) cl_s[tid] = clustering[(size_t)b * 16 + tid];
    __syncthreads();
    float m = -INFINITY, s = 0.f;
    for (int g = tid; g < G_total; g += blockDim.x) {
        const float4* r4 = (const float4*)(rw + (size_t)g * 16);
        float d = 0.f;
#pragma unroll
        for (int q = 0; q < 4; ++q) {
            float4 v = r4[q];
            d = fmaf(cl_s[4 * q + 0], v.x, d);
            d = fmaf(cl_s[4 * q + 1], v.y, d);
            d = fmaf(cl_s[4 * q + 2], v.z, d);
            d = fmaf(cl_s[4 * q + 3], v.w, d);
        }
        float logit = logrb[g] + d;
        float mn = fmaxf(m, logit);
        s = s * __expf(m - mn) + __expf(logit - mn);
        m = mn;
    }
    __shared__ float ms[256], ss[256];
    ms[tid] = m; ss[tid] = s;
    __syncthreads();
    for (int o = 128; o > 0; o >>= 1) {
        if (tid < o) {
            float m2 = ms[tid + o], s2 = ss[tid + o];
            float mn = fmaxf(ms[tid], m2);
            ss[tid] = ss[tid] * __expf(ms[tid] - mn) + s2 * __expf(m2 - mn);
            ms[tid] = mn;
        }
        __syncthreads();
    }
    if (tid == 0) lse[b] = ms[0] + __logf(ss[0]);
}

// ---------------------------------------------------------------------------
// Fused: histogram over gm  +  lik_overall term (coalesced, no scatter needed).
__global__ void k_histlik(const int* __restrict__ lcx, const int* __restrict__ lc2,
                          int* __restrict__ counts,
                          const float* __restrict__ clustering, const float* __restrict__ rw,
                          const float* __restrict__ logrb, const float* __restrict__ lse,
                          float* __restrict__ pC, int N, int G_oi, int G_total, float logGt) {
    const int i = blockIdx.x * blockDim.x + threadIdx.x;
    float acc = 0.f;
    if (i < N) {
        atomicAdd(&counts[(unsigned)lcx[i] % (unsigned)G_oi], 1);
        const int v = lc2[i];
        const unsigned b2 = (unsigned)v / (unsigned)G_total;
        const unsigned gt = (unsigned)v - b2 * (unsigned)G_total;
        const float4* c4 = (const float4*)(clustering + (size_t)b2 * 16);
        const float4* r4 = (const float4*)(rw + (size_t)gt * 16);
        float d2 = 0.f;
#pragma unroll
        for (int q = 0; q < 4; ++q) {
            float4 a = c4[q], b = r4[q];
            d2 = fmaf(a.x, b.x, d2); d2 = fmaf(a.y, b.y, d2);
            d2 = fmaf(a.z, b.z, d2); d2 = fmaf(a.w, b.w, d2);
        }
        acc = -(logrb[gt] + d2 - lse[b2] + logGt);
    }
    acc = wave_sum(acc);
    __shared__ float wsm[4];
    if ((threadIdx.x & 63) == 0) wsm[threadIdx.x >> 6] = acc;
    __syncthreads();
    if (threadIdx.x == 0)
        atomicAdd(pC, wsm[0] + wsm[1] + wsm[2] + wsm[3]);
}

// ---------------------------------------------------------------------------
__global__ void k_scan(const int* __restrict__ counts, int* __restrict__ offsets,
                       int* __restrict__ cursor, int G_oi) {
    __shared__ int sm[512];
    const int t = threadIdx.x;
    int v = (t < G_oi) ? counts[t] : 0;
    sm[t] = v;
    __syncthreads();
    for (int o = 1; o < 512; o <<= 1) {
        int add = (t >= o) ? sm[t - o] : 0;
        __syncthreads();
        sm[t] += add;
        __syncthreads();
    }
    if (t < G_oi) {
        offsets[t + 1] = sm[t];
        cursor[t] = sm[t] - v;
    }
    if (t == 0) offsets[0] = 0;
}

// ---------------------------------------------------------------------------
// Scatter: one packed int2 per cut: (x bits, (b1<<16)|gh)
__global__ void k_scatter(const float* __restrict__ coord, const int* __restrict__ lgix,
                          const int* __restrict__ lcx, int* __restrict__ cursor,
                          int2* __restrict__ packed, int N, int G_oi) {
    int i = blockIdx.x * blockDim.x + threadIdx.x;
    if (i >= N) return;
    unsigned v = (unsigned)lcx[i];
    unsigned g = v % (unsigned)G_oi;
    int pos = atomicAdd(&cursor[g], 1);
    packed[pos] = make_int2(__float_as_int(coord[i]),
                            (int)(((v / (unsigned)G_oi) << 16) | (unsigned)lgix[i]));
}

// ---------------------------------------------------------------------------
// Main: one block per mixture-gene bucket, one thread per cut.
// lw rows staged in LDS (uniform-address ds_read broadcast).
__launch_bounds__(512)
__global__ void k_main2(const int2* __restrict__ packed,
                        const int* __restrict__ offsets,
                        const float* __restrict__ clustering,
                        const float* __restrict__ lwT,    // [g][224][16], pre-scaled by log2e
                        const float4* __restrict__ pk,    // [g_h][224]
                        float* __restrict__ pA, int G_oi) {
    const int g = blockIdx.x;
    const int tid = threadIdx.x;
    __shared__ float lds_lw[3584];
    {
        const float* src = lwT + (size_t)g * 3584;
        for (int k = tid; k < 3584; k += 512) lds_lw[k] = src[k];
    }
    __syncthreads();
    const int s = offsets[g], e = offsets[g + 1];
    float acc = 0.f;

    for (int base = s; base < e; base += 512) {
        const int i = base + tid;
        if (i < e) {
            const int2 p = packed[i];
            float x = __int_as_float(p.x);
            const int b1 = (int)((unsigned)p.y >> 16);
            const int gh = p.y & 0xffff;
            const float4* pkh = pk + (size_t)gh * 224;

            float cl[16];
            {
                const float4* c4 = (const float4*)(clustering + (size_t)b1 * 16);
#pragma unroll
                for (int q = 0; q < 4; ++q) {
                    float4 v = c4[q];
                    cl[4 * q + 0] = v.x; cl[4 * q + 1] = v.y;
                    cl[4 * q + 2] = v.z; cl[4 * q + 3] = v.w;
                }
            }
            const float4 uh0 = pkh[127];
            const float uh0v[3] = {uh0.x, uh0.y, uh0.z};

            float lad = 0.f;
            const int NH[3] = {128, 64, 32};
            const int OH[3] = {0, 128, 192};
            const int SO[3] = {0, 128, 191};
#pragma unroll
            for (int lev = 0; lev < 3; ++lev) {
                const int nw = NH[lev] - 1;
                const float* rowbase = lds_lw + (size_t)OH[lev] * 16;
                float hp;
                {
                    const float4* rq = (const float4*)rowbase;
                    float4 r0 = rq[0], r1 = rq[1], r2 = rq[2], r3 = rq[3];
                    float d0 = fmaf(cl[3], r0.w, fmaf(cl[2], r0.z, fmaf(cl[1], r0.y, cl[0] * r0.x)));
                    float d1 = fmaf(cl[7], r1.w, fmaf(cl[6], r1.z, fmaf(cl[5], r1.y, cl[4] * r1.x)));
                    float d2 = fmaf(cl[11], r2.w, fmaf(cl[10], r2.z, fmaf(cl[9], r2.y, cl[8] * r2.x)));
                    float d3 = fmaf(cl[15], r3.w, fmaf(cl[14], r3.z, fmaf(cl[13], r3.y, cl[12] * r3.x)));
                    hp = exp2f(uh0v[lev] + (d0 + d1) + (d2 + d3));
                }
                float h_l = hp, h_r = hp, whb = 0.f, loc_l = 0.f, cdf = 0.f, area = 0.f;
                int in = 0;
                const float4* pks = pkh + SO[lev];
                float4 pkv = pks[0];
                for (int j = 0; j < nw; ++j) {
                    float4 pknext = pks[j + 1];      // always in-bounds by layout
                    const float4* rq = (const float4*)(rowbase + (size_t)(j + 1) * 16);
                    float4 r0 = rq[0], r1 = rq[1], r2 = rq[2], r3 = rq[3];
                    float d0 = fmaf(cl[3], r0.w, fmaf(cl[2], r0.z, fmaf(cl[1], r0.y, cl[0] * r0.x)));
                    float d1 = fmaf(cl[7], r1.w, fmaf(cl[6], r1.z, fmaf(cl[5], r1.y, cl[4] * r1.x)));
                    float d2 = fmaf(cl[11], r2.w, fmaf(cl[10], r2.z, fmaf(cl[9], r2.y, cl[8] * r2.x)));
                    float d3 = fmaf(cl[15], r3.w, fmaf(cl[14], r3.z, fmaf(cl[13], r3.y, cl[12] * r3.x)));
                    float hn = exp2f(pkv.x + (d0 + d1) + (d2 + d3));
                    float seg = (hp + hn) * pkv.y;
                    if (in == j) { h_r = hn; whb = pkv.y; }
                    bool adv = (x >= pkv.z) && (j < nw - 1);
                    if (adv) { cdf += seg; h_l = hn; loc_l = pkv.z; in = j + 1; }
                    area += seg;
                    hp = hn;
                    pkv = pknext;
                }
                float inv_area = __builtin_amdgcn_rcpf(area);
                float alpha = (x - loc_l) * 0.5f * __builtin_amdgcn_rcpf(whb);
                float t2 = whb * alpha;
                x = (t2 * fmaf(h_r - h_l, alpha, 2.f * h_l) + cdf) * inv_area;
                lad += __logf(fmaf(h_r - h_l, alpha, h_l)) - __logf(area);
            }
            acc -= lad;
        }
    }

    acc = wave_sum(acc);
    __shared__ float wsm[8];
    if ((tid & 63) == 0) wsm[tid >> 6] = acc;
    __syncthreads();
    if (tid == 0) {
        float t = 0.f;
#pragma unroll
        for (int w = 0; w < 8; ++w) t += wsm[w];
        pA[g] = t;
    }
}

// ---------------------------------------------------------------------------
__global__ void k_final(const float* __restrict__ pA, const float* __restrict__ pB,
                        const float* __restrict__ pC, float* __restrict__ out, int nA, int nB) {
    const int tid = threadIdx.x;
    float acc = 0.f;
    for (int i = tid; i < nA; i += blockDim.x) acc += pA[i];
    for (int i = tid; i < nB; i += blockDim.x) acc += pB[i];
    if (tid == 0) acc += pC[0];
    __shared__ float sm[256];
    sm[tid] = acc;
    __syncthreads();
    for (int o = 128; o > 0; o >>= 1) { if (tid < o) sm[tid] += sm[tid + o]; __syncthreads(); }
    if (tid == 0) out[0] = sm[0];
}

// ---------------------------------------------------------------------------
extern "C" void kernel_launch(void* const* d_in, const int* in_sizes, int n_in,
                              void* d_out, int out_size, void* d_ws, size_t ws_size,
                              hipStream_t stream) {
    const float* clustering        = (const float*)d_in[0];
    const float* coordinates       = (const float*)d_in[1];
    const int*   genes_oi          = (const int*)d_in[2];
    const int*   local_gene_ix     = (const int*)d_in[3];
    const int*   local_cellxgene_ix= (const int*)d_in[4];
    const int*   localcellxgene_ix = (const int*)d_in[5];
    const float* lw                = (const float*)d_in[6];
    const float* rw                = (const float*)d_in[7];
    const float* rho_bias          = (const float*)d_in[8];
    const float* uh                = (const float*)d_in[9];
    const float* uw                = (const float*)d_in[10];

    const int G_total = in_sizes[8];                  // 20000
    const int G_oi    = in_sizes[2];                  // 500
    const int N       = in_sizes[1];                  // 200000
    const int L       = in_sizes[7] / G_total;        // 16
    const int B       = in_sizes[0] / L;              // 512

    size_t off = 0;
    char* base = (char*)d_ws;
    auto alloc = [&](size_t nbytes) {
        char* p = base + off;
        off = (off + nbytes + 15) & ~(size_t)15;
        return (void*)p;
    };
    float*  pA      = (float*)alloc(sizeof(float) * (G_oi + 16));
    float*  pB      = (float*)alloc(sizeof(float) * (G_oi + 16));
    float*  pC      = (float*)alloc(sizeof(float) * 16);
    float*  lse     = (float*)alloc(sizeof(float) * (B + 16));
    float*  logrb   = (float*)alloc(sizeof(float) * G_total);
    float*  lwT     = (float*)alloc(sizeof(float) * (size_t)G_oi * 3584);
    float4* pk      = (float4*)alloc(sizeof(float4) * (size_t)G_oi * 224);
    int*    counts  = (int*)alloc(sizeof(int) * 512);
    int*    offsets = (int*)alloc(sizeof(int) * 512);
    int*    cursor  = (int*)alloc(sizeof(int) * 512);
    int2*   packed  = (int2*)alloc(sizeof(int2) * (size_t)N);
    (void)ws_size;

    const float logGt = logf((float)G_total);
    const int TPB = 256;

    k_prep<<<G_oi, 256, 0, stream>>>(genes_oi, uh, uw, lw, rw, pk, lwT, pB);
    k_init<<<(G_total + TPB - 1) / TPB, TPB, 0, stream>>>(rho_bias, logrb, counts, pC, G_total);
    k_lse<<<B, 256, 0, stream>>>(clustering, rw, logrb, lse, G_total);
    k_histlik<<<(N + TPB - 1) / TPB, TPB, 0, stream>>>(local_cellxgene_ix, localcellxgene_ix,
                                                       counts, clustering, rw, logrb, lse,
                                                       pC, N, G_oi, G_total, logGt);
    k_scan<<<1, 512, 0, stream>>>(counts, offsets, cursor, G_oi);
    k_scatter<<<(N + TPB - 1) / TPB, TPB, 0, stream>>>(coordinates, local_gene_ix,
                                                       local_cellxgene_ix, cursor, packed, N, G_oi);
    k_main2<<<G_oi, 512, 0, stream>>>(packed, offsets, clustering, lwT, pk, pA, G_oi);
    k_final<<<1, 256, 0, stream>>>(pA, pB, pC, (float*)d_out, G_oi, G_oi);
}